// Round 1
// baseline (2812.871 us; speedup 1.0000x reference)
//
#include <hip/hip_runtime.h>
#include <math.h>

#define NN    100000
#define FEATS 512
#define HID   64
#define EE    3200000

// ---------------------------------------------------------------- degrees
__global__ void degrees_kernel(const int* __restrict__ src, const int* __restrict__ dst,
                               int* __restrict__ dout, int* __restrict__ din) {
  int stride = gridDim.x * blockDim.x;
  for (int e = blockIdx.x * blockDim.x + threadIdx.x; e < EE; e += stride) {
    atomicAdd(&dout[src[e]], 1);
    atomicAdd(&din[dst[e]], 1);
  }
}

__global__ void node_prep(const int* __restrict__ dout, const int* __restrict__ din,
                          float* __restrict__ r_out, float* __restrict__ r_in) {
  int i = blockIdx.x * 256 + threadIdx.x;
  if (i >= NN) return;
  int a = dout[i]; if (a < 1) a = 1;
  int b = din[i];  if (b < 1) b = 1;
  r_out[i] = rsqrtf((float)a);
  r_in[i]  = rsqrtf((float)b);
}

// ---------------------------------------------------------------- scan (row_ptr)
__global__ void scan_local(const int* __restrict__ din, int* __restrict__ row_ptr,
                           int* __restrict__ bsums) {
  __shared__ int s[256];
  int t = threadIdx.x;
  int i = blockIdx.x * 256 + t;
  s[t] = (i < NN) ? din[i] : 0;
  __syncthreads();
  for (int off = 1; off < 256; off <<= 1) {
    int add = (t >= off) ? s[t - off] : 0;
    __syncthreads();
    s[t] += add;
    __syncthreads();
  }
  if (i < NN) row_ptr[i + 1] = s[t];
  if (t == 255) bsums[blockIdx.x] = s[t];
  if (blockIdx.x == 0 && t == 0) row_ptr[0] = 0;
}

__global__ void scan_bsums(int* __restrict__ bsums, int nb) {
  __shared__ int s[512];
  int t = threadIdx.x;
  s[t] = (t < nb) ? bsums[t] : 0;
  __syncthreads();
  for (int off = 1; off < 512; off <<= 1) {
    int add = (t >= off) ? s[t - off] : 0;
    __syncthreads();
    s[t] += add;
    __syncthreads();
  }
  if (t < nb) bsums[t] = s[t];
}

__global__ void scan_add(int* __restrict__ row_ptr, const int* __restrict__ bsums) {
  int b = blockIdx.x;
  if (b == 0) return;
  int i = b * 256 + threadIdx.x;
  if (i < NN) row_ptr[i + 1] += bsums[b - 1];
}

__global__ void csr_scatter(const int* __restrict__ src, const int* __restrict__ dst,
                            const int* __restrict__ row_ptr, int* __restrict__ fill,
                            int* __restrict__ col) {
  int stride = gridDim.x * blockDim.x;
  for (int e = blockIdx.x * blockDim.x + threadIdx.x; e < EE; e += stride) {
    int d = dst[e];
    int pos = row_ptr[d] + atomicAdd(&fill[d], 1);
    col[pos] = src[e];
  }
}

// ---------------------------------------------------------------- GEMM1: h = relu(x@w1+b1)
__global__ __launch_bounds__(256) void gemm1_kernel(const float* __restrict__ x,
                                                    const float* __restrict__ w1,
                                                    const float* __restrict__ b1,
                                                    float* __restrict__ h) {
  __shared__ float xs[64][16];
  __shared__ float ws[16][64];
  int t = threadIdx.x;
  int row0 = blockIdx.x * 64;
  int tx = t & 15, ty = t >> 4;
  int lr = t >> 2, lq = t & 3;           // xs load mapping
  int wk = t >> 4, wc = (t & 15) * 4;    // ws load mapping
  float acc[4][4] = {};
  for (int k0 = 0; k0 < FEATS; k0 += 16) {
    float4 xv = make_float4(0.f, 0.f, 0.f, 0.f);
    int gr = row0 + lr;
    if (gr < NN) xv = *reinterpret_cast<const float4*>(x + (size_t)gr * FEATS + k0 + lq * 4);
    float4 wv = *reinterpret_cast<const float4*>(w1 + (size_t)(k0 + wk) * HID + wc);
    xs[lr][lq * 4 + 0] = xv.x; xs[lr][lq * 4 + 1] = xv.y;
    xs[lr][lq * 4 + 2] = xv.z; xs[lr][lq * 4 + 3] = xv.w;
    ws[wk][wc + 0] = wv.x; ws[wk][wc + 1] = wv.y;
    ws[wk][wc + 2] = wv.z; ws[wk][wc + 3] = wv.w;
    __syncthreads();
#pragma unroll
    for (int kk = 0; kk < 16; ++kk) {
      float a[4], b[4];
#pragma unroll
      for (int ii = 0; ii < 4; ++ii) a[ii] = xs[ty * 4 + ii][kk];
#pragma unroll
      for (int jj = 0; jj < 4; ++jj) b[jj] = ws[kk][tx * 4 + jj];
#pragma unroll
      for (int ii = 0; ii < 4; ++ii)
#pragma unroll
        for (int jj = 0; jj < 4; ++jj) acc[ii][jj] = fmaf(a[ii], b[jj], acc[ii][jj]);
    }
    __syncthreads();
  }
  float bb0 = b1[tx * 4 + 0], bb1 = b1[tx * 4 + 1];
  float bb2 = b1[tx * 4 + 2], bb3 = b1[tx * 4 + 3];
#pragma unroll
  for (int ii = 0; ii < 4; ++ii) {
    int gr = row0 + ty * 4 + ii;
    if (gr < NN) {
      float4 o;
      o.x = fmaxf(acc[ii][0] + bb0, 0.f);
      o.y = fmaxf(acc[ii][1] + bb1, 0.f);
      o.z = fmaxf(acc[ii][2] + bb2, 0.f);
      o.w = fmaxf(acc[ii][3] + bb3, 0.f);
      *reinterpret_cast<float4*>(h + (size_t)gr * HID + tx * 4) = o;
    }
  }
}

// ---------------------------------------------------------------- GEMM2 + softmax + err init
__global__ __launch_bounds__(256) void gemm2_softmax(const float* __restrict__ h,
                                                     const float* __restrict__ w2,
                                                     const float* __restrict__ b2,
                                                     const int* __restrict__ mask,
                                                     const int* __restrict__ labels,
                                                     float* __restrict__ p,
                                                     float* __restrict__ err) {
  __shared__ float w2s[64 * 64];
  int t = threadIdx.x;
  for (int idx = t; idx < 64 * 64; idx += 256) w2s[idx] = w2[idx];
  __syncthreads();
  int wave = t >> 6, lane = t & 63;
  int base = blockIdx.x * 32;
  float bb = b2[lane];
  for (int r = 0; r < 8; ++r) {
    int i = base + r * 4 + wave;
    if (i >= NN) break;
    float hv = h[(size_t)i * HID + lane];
    float acc = bb;
#pragma unroll
    for (int k = 0; k < 64; ++k)
      acc = fmaf(__shfl(hv, k), w2s[k * 64 + lane], acc);
    float m = acc;
#pragma unroll
    for (int off = 32; off >= 1; off >>= 1) m = fmaxf(m, __shfl_xor(m, off));
    float ev = __expf(acc - m);
    float sum = ev;
#pragma unroll
    for (int off = 32; off >= 1; off >>= 1) sum += __shfl_xor(sum, off);
    float pv = ev / sum;
    size_t off64 = (size_t)i * 64 + lane;
    p[off64] = pv;
    float oh = (mask[i] != 0 && labels[i] == lane) ? 1.f : 0.f;
    err[off64] = oh - pv;
  }
}

// ---------------------------------------------------------------- graph conv (SpMM, CSR-by-dst)
// MODE 0: out = train ? in : r_in*sum          (loop 1; train rows carry h0 invariantly)
// MODE 1: out = 0.9*r_in*sum + 0.1*h0          (loop 2)
// MODE 2: out = log(0.9*r_in*sum + 0.1*h0 + 1) (loop 2 final, fused epilogue)
template <int MODE>
__global__ __launch_bounds__(256) void conv_kernel(const int* __restrict__ row_ptr,
                                                   const int* __restrict__ col,
                                                   const float* __restrict__ r_out,
                                                   const float* __restrict__ r_in,
                                                   const int* __restrict__ mask,
                                                   const float* __restrict__ in,
                                                   const float* __restrict__ h0,
                                                   float* __restrict__ out) {
  int wid = (blockIdx.x * 256 + threadIdx.x) >> 6;  // one wave per node
  int lane = threadIdx.x & 63;                      // lane = feature
  if (wid >= NN) return;
  size_t off = (size_t)wid * 64 + lane;
  if (MODE == 0) {
    if (mask[wid] != 0) { out[off] = in[off]; return; }  // wave-uniform branch
  }
  int s0 = row_ptr[wid], s1 = row_ptr[wid + 1];
  float sum = 0.f;
  int e = s0;
  for (; e + 8 <= s1; e += 8) {   // 8-deep gather batch keeps vmcnt pipeline full
    int cc[8]; float wv[8]; float vv[8];
#pragma unroll
    for (int j = 0; j < 8; ++j) cc[j] = col[e + j];
#pragma unroll
    for (int j = 0; j < 8; ++j) wv[j] = r_out[cc[j]];
#pragma unroll
    for (int j = 0; j < 8; ++j) vv[j] = in[(size_t)cc[j] * 64 + lane];
#pragma unroll
    for (int j = 0; j < 8; ++j) sum = fmaf(wv[j], vv[j], sum);
  }
  for (; e < s1; ++e) {
    int c = col[e];
    sum = fmaf(r_out[c], in[(size_t)c * 64 + lane], sum);
  }
  sum *= r_in[wid];
  if (MODE == 0) {
    out[off] = sum;
  } else {
    float o = 0.9f * sum + 0.1f * h0[off];
    if (MODE == 2) o = logf(o + 1.f);
    out[off] = o;
  }
}

// ---------------------------------------------------------------- h0_2 = p + err_final
__global__ void combine_kernel(const float* __restrict__ p, const float* __restrict__ err,
                               float* __restrict__ h02) {
  int idx = blockIdx.x * 256 + threadIdx.x;
  if (idx < NN * HID / 4) {
    float4 a = reinterpret_cast<const float4*>(p)[idx];
    float4 b = reinterpret_cast<const float4*>(err)[idx];
    float4 o;
    o.x = a.x + b.x; o.y = a.y + b.y; o.z = a.z + b.z; o.w = a.w + b.w;
    reinterpret_cast<float4*>(h02)[idx] = o;
  }
}

// ---------------------------------------------------------------- launch
extern "C" void kernel_launch(void* const* d_in, const int* in_sizes, int n_in,
                              void* d_out, int out_size, void* d_ws, size_t ws_size,
                              hipStream_t stream) {
  const float* x      = (const float*)d_in[0];
  const float* w1     = (const float*)d_in[1];
  const float* b1     = (const float*)d_in[2];
  const float* w2     = (const float*)d_in[3];
  const float* b2     = (const float*)d_in[4];
  const int*   edges  = (const int*)d_in[5];
  const int*   mask   = (const int*)d_in[6];
  const int*   labels = (const int*)d_in[7];
  const int*   src = edges;
  const int*   dst = edges + EE;

  char* w = (char*)d_ws;
  auto alloc = [&](size_t bytes) -> char* {
    char* pp = w;
    w += (bytes + 255) & ~(size_t)255;
    return pp;
  };
  int*   col     = (int*)alloc((size_t)EE * 4);
  int*   deg_out = (int*)alloc((size_t)NN * 4);
  int*   deg_in  = (int*)alloc((size_t)NN * 4);
  int*   fillc   = (int*)alloc((size_t)NN * 4);
  int*   row_ptr = (int*)alloc((size_t)(NN + 1) * 4);
  int*   bsums   = (int*)alloc(512 * 4);
  float* r_out   = (float*)alloc((size_t)NN * 4);
  float* r_in    = (float*)alloc((size_t)NN * 4);
  float* W1      = (float*)alloc((size_t)NN * HID * 4);  // h, later h0_2
  float* W2      = (float*)alloc((size_t)NN * HID * 4);  // p
  float* A       = (float*)alloc((size_t)NN * HID * 4);  // ping
  float* Bb      = (float*)d_out;                        // pong (d_out doubles as scratch)

  // zero deg_out / deg_in / fill (contiguous region incl. alignment pads)
  size_t zlen = (size_t)((char*)fillc + (size_t)NN * 4 - (char*)deg_out);
  hipMemsetAsync(deg_out, 0, zlen, stream);

  const int SCAN_NB = (NN + 255) / 256;  // 391

  degrees_kernel<<<2048, 256, 0, stream>>>(src, dst, deg_out, deg_in);
  node_prep<<<SCAN_NB, 256, 0, stream>>>(deg_out, deg_in, r_out, r_in);
  scan_local<<<SCAN_NB, 256, 0, stream>>>(deg_in, row_ptr, bsums);
  scan_bsums<<<1, 512, 0, stream>>>(bsums, SCAN_NB);
  scan_add<<<SCAN_NB, 256, 0, stream>>>(row_ptr, bsums);
  csr_scatter<<<2048, 256, 0, stream>>>(src, dst, row_ptr, fillc, col);

  gemm1_kernel<<<(NN + 63) / 64, 256, 0, stream>>>(x, w1, b1, W1);
  gemm2_softmax<<<(NN + 31) / 32, 256, 0, stream>>>(W1, w2, b2, mask, labels, W2, A);

  const int CONV_GRID = (NN + 3) / 4;  // 25000 blocks, 4 waves (nodes) per block

  // loop 1: err propagation with train reset (invariant: train rows hold h0)
  {
    float* in = A; float* out = Bb;
    for (int it = 0; it < 10; ++it) {
      conv_kernel<0><<<CONV_GRID, 256, 0, stream>>>(row_ptr, col, r_out, r_in, mask, in, nullptr, out);
      float* tmp = in; in = out; out = tmp;
    }
    // 10 iterations: result ends in A
  }

  // h0_2 = p + err_final  (into W1; h no longer needed)
  combine_kernel<<<NN * HID / 4 / 256, 256, 0, stream>>>(W2, A, W1);

  // loop 2: smoothing; final iteration fuses log(out+1) into d_out
  conv_kernel<1><<<CONV_GRID, 256, 0, stream>>>(row_ptr, col, r_out, r_in, mask, W1, W1, A);
  {
    float* in = A; float* out = Bb;
    for (int it = 1; it < 9; ++it) {
      conv_kernel<1><<<CONV_GRID, 256, 0, stream>>>(row_ptr, col, r_out, r_in, mask, in, W1, out);
      float* tmp = in; in = out; out = tmp;
    }
    // after 9 total MODE<=1 iterations, current value is in A
    conv_kernel<2><<<CONV_GRID, 256, 0, stream>>>(row_ptr, col, r_out, r_in, mask, A, W1, (float*)d_out);
  }
}